// Round 1
// baseline (114.270 us; speedup 1.0000x reference)
//
#include <hip/hip_runtime.h>

// ---------------------------------------------------------------------------
// Precompute kernel (1 block, 64 threads):
//  Phase 1: threads 0..7 build column t of the fixed 8x8 unitary U composed
//           from the theta gates (order matches reference).
//  Phase 2: threads 0..31 contract |U psi|^2 quadratic forms with W1/b1/W2
//           into per-hidden-unit coefficients T[3][3] over the basis
//           (1, cos x0, sin x0) x (1, cos x1, sin x1).
//  Table layout (floats): row l (stride 12): [T01 T02 T10 T20 T11 T12 T21 T22
//           bias  w2_l0  w2_l1  pad];  [384..385] = b2; [386..387] pad.
// ---------------------------------------------------------------------------
__global__ __launch_bounds__(64) void q_precompute(
    const float* __restrict__ theta,
    const float* __restrict__ W1,   // (8,32)
    const float* __restrict__ b1,   // (32,)
    const float* __restrict__ W2,   // (32,2)
    const float* __restrict__ b2,   // (2,)
    float* __restrict__ tab)
{
    __shared__ float Ure[8][8];
    __shared__ float Uim[8][8];
    const int t = threadIdx.x;

    if (t < 8) {
        float cr[8], ci[8];
        #pragma unroll
        for (int r = 0; r < 8; ++r) { cr[r] = (r == t) ? 1.f : 0.f; ci[r] = 0.f; }

        // RX on pair (a,b):  a' = c*a + (-i s)*b ; b' = (-i s)*a + c*b
        auto rxmix = [&](int a, int b, float c_, float s_) {
            float ar = cr[a], ai = ci[a], br = cr[b], bi = ci[b];
            cr[a] = c_*ar + s_*bi;   ci[a] = c_*ai - s_*br;
            cr[b] = s_*ai + c_*br;   ci[b] = -s_*ar + c_*bi;
        };
        // RY on pair (a,b):  a' = c*a - s*b ; b' = s*a + c*b  (real coeffs)
        auto rymix = [&](int a, int b, float c_, float s_) {
            float ar = cr[a], ai = ci[a], br = cr[b], bi = ci[b];
            cr[a] = c_*ar - s_*br;   ci[a] = c_*ai - s_*bi;
            cr[b] = s_*ar + c_*br;   ci[b] = s_*ai + c_*bi;
        };
        // multiply row r by (u + i v)
        auto zmul = [&](int r, float u, float v) {
            float xr = cr[r], xi = ci[r];
            cr[r] = xr*u - xi*v;  ci[r] = xr*v + xi*u;
        };

        float c, s;
        // index = 4*i0 + 2*i1 + i2  (wire0 = MSB)
        c = cosf(theta[0]*0.5f); s = sinf(theta[0]*0.5f);           // RX wire0
        rxmix(0,4,c,s); rxmix(1,5,c,s); rxmix(2,6,c,s); rxmix(3,7,c,s);
        c = cosf(theta[1]*0.5f); s = sinf(theta[1]*0.5f);           // RY wire1
        rymix(0,2,c,s); rymix(1,3,c,s); rymix(4,6,c,s); rymix(5,7,c,s);
        c = cosf(theta[2]*0.5f); s = sinf(theta[2]*0.5f);           // RZ wire2
        #pragma unroll
        for (int r = 0; r < 8; ++r) zmul(r, c, (r & 1) ? s : -s);
        c = cosf(theta[3]*0.5f); s = sinf(theta[3]*0.5f);           // CRX 0->1
        rxmix(4,6,c,s); rxmix(5,7,c,s);
        c = cosf(theta[4]*0.5f); s = sinf(theta[4]*0.5f);           // RY wire2
        rymix(0,1,c,s); rymix(2,3,c,s); rymix(4,5,c,s); rymix(6,7,c,s);
        c = cosf(theta[5]*0.5f); s = sinf(theta[5]*0.5f);           // RX wire1
        rxmix(0,2,c,s); rxmix(1,3,c,s); rxmix(4,6,c,s); rxmix(5,7,c,s);
        c = cosf(theta[6]*0.5f); s = sinf(theta[6]*0.5f);           // CRX 1->2
        rxmix(2,3,c,s); rxmix(6,7,c,s);
        c = cosf(theta[7]*0.5f); s = sinf(theta[7]*0.5f);           // RZ wire0
        #pragma unroll
        for (int r = 0; r < 8; ++r) zmul(r, c, (r < 4) ? -s : s);

        #pragma unroll
        for (int r = 0; r < 8; ++r) { Ure[r][t] = cr[r]; Uim[r][t] = ci[r]; }
    }
    __syncthreads();

    if (t < 32) {
        // W[:,m] = U[:,col(m)] * phase, col = {0,2,4,6}, phase = {1,1,-i,-i}
        float Wre[8][4], Wim[8][4];
        #pragma unroll
        for (int j = 0; j < 8; ++j) {
            Wre[j][0] =  Ure[j][0]; Wim[j][0] =  Uim[j][0];
            Wre[j][1] =  Ure[j][2]; Wim[j][1] =  Uim[j][2];
            Wre[j][2] =  Uim[j][4]; Wim[j][2] = -Ure[j][4];
            Wre[j][3] =  Uim[j][6]; Wim[j][3] = -Ure[j][6];
        }
        // Q_l[m][n] = sum_j W1[j,l] (ReW_jm ReW_jn + ImW_jm ImW_jn)
        float Q[4][4];
        #pragma unroll
        for (int m = 0; m < 4; ++m)
            #pragma unroll
            for (int n = 0; n < 4; ++n) Q[m][n] = 0.f;
        for (int j = 0; j < 8; ++j) {
            float w = W1[j*32 + t];
            #pragma unroll
            for (int m = 0; m < 4; ++m)
                #pragma unroll
                for (int n = 0; n < 4; ++n)
                    Q[m][n] = fmaf(w, Wre[j][m]*Wre[j][n] + Wim[j][m]*Wim[j][n], Q[m][n]);
        }
        // collapse p_m p_n -> monomials (c^2, cs, s^2) per wire
        float R[3][3];
        R[0][0] = Q[0][0];
        R[0][1] = Q[0][1] + Q[1][0];
        R[0][2] = Q[1][1];
        R[1][0] = Q[0][2] + Q[2][0];
        R[1][1] = Q[0][3] + Q[1][2] + Q[2][1] + Q[3][0];
        R[1][2] = Q[1][3] + Q[3][1];
        R[2][0] = Q[2][2];
        R[2][1] = Q[2][3] + Q[3][2];
        R[2][2] = Q[3][3];
        // change of basis: (c^2, cs, s^2) = A (1, cos x, sin x);  T = A^T R A
        float P[3][3];
        #pragma unroll
        for (int b = 0; b < 3; ++b) {
            P[0][b] = 0.5f*(R[0][b] + R[2][b]);
            P[1][b] = 0.5f*(R[0][b] - R[2][b]);
            P[2][b] = 0.5f*R[1][b];
        }
        float T[3][3];
        #pragma unroll
        for (int si = 0; si < 3; ++si) {
            T[si][0] = 0.5f*(P[si][0] + P[si][2]);
            T[si][1] = 0.5f*(P[si][0] - P[si][2]);
            T[si][2] = 0.5f*P[si][1];
        }
        float* row = tab + t*12;
        row[0] = T[0][1]; row[1] = T[0][2]; row[2] = T[1][0]; row[3] = T[2][0];
        row[4] = T[1][1]; row[5] = T[1][2]; row[6] = T[2][1]; row[7] = T[2][2];
        row[8] = b1[t] + T[0][0];
        row[9]  = W2[t*2+0];
        row[10] = W2[t*2+1];
        row[11] = 0.f;
    }
    if (t == 0) { tab[384] = b2[0]; tab[385] = b2[1]; tab[386] = 0.f; tab[387] = 0.f; }
}

// ---------------------------------------------------------------------------
// Main kernel: 4 elements per thread. float4 loads (12B/elem, 48B/thread is
// 16B aligned), table staged in LDS (uniform broadcast reads, conflict-free).
// ---------------------------------------------------------------------------
__global__ __launch_bounds__(256) void q_main(
    const float* __restrict__ x,
    const float* __restrict__ tab,
    float* __restrict__ out,
    int B)
{
    __shared__ float4 lt[97];   // 388 floats
    const int lid = threadIdx.x;
    if (lid < 97) lt[lid] = ((const float4*)tab)[lid];
    __syncthreads();

    const int t = blockIdx.x * 256 + lid;
    const int base = t * 4;
    if (base >= B) return;

    const float* ltf = (const float*)lt;
    const float b2a = ltf[384], b2b = ltf[385];

    if (base + 4 <= B) {
        const float4* X4 = (const float4*)x;
        float4 xa = X4[t*3+0], xb = X4[t*3+1], xc = X4[t*3+2];
        // element k uses (x[3k], x[3k+1]); x[3k+2] is provably dead (global phase)
        float a0[4] = {xa.x, xa.w, xb.z, xc.y};
        float a1[4] = {xa.y, xb.x, xb.w, xc.z};

        float C0[4], S0[4], C1[4], S1[4], P00[4], P01[4], P10[4], P11[4];
        #pragma unroll
        for (int k = 0; k < 4; ++k) {
            __sincosf(a0[k], &S0[k], &C0[k]);
            __sincosf(a1[k], &S1[k], &C1[k]);
            P00[k] = C0[k]*C1[k]; P01[k] = C0[k]*S1[k];
            P10[k] = S0[k]*C1[k]; P11[k] = S0[k]*S1[k];
        }
        float acc0[4] = {b2a, b2a, b2a, b2a};
        float acc1[4] = {b2b, b2b, b2b, b2b};

        #pragma unroll 2
        for (int l = 0; l < 32; ++l) {
            float4 cA = lt[l*3+0];   // T01 T02 T10 T20
            float4 cB = lt[l*3+1];   // T11 T12 T21 T22
            float4 cC = lt[l*3+2];   // bias w2a w2b pad
            #pragma unroll
            for (int k = 0; k < 4; ++k) {
                float h = cC.x;
                h = fmaf(cA.x, C1[k],  h);
                h = fmaf(cA.y, S1[k],  h);
                h = fmaf(cA.z, C0[k],  h);
                h = fmaf(cA.w, S0[k],  h);
                h = fmaf(cB.x, P00[k], h);
                h = fmaf(cB.y, P01[k], h);
                h = fmaf(cB.z, P10[k], h);
                h = fmaf(cB.w, P11[k], h);
                h = fmaxf(h, 0.f);
                acc0[k] = fmaf(h, cC.y, acc0[k]);
                acc1[k] = fmaf(h, cC.z, acc1[k]);
            }
        }
        float4* O4 = (float4*)out;
        O4[t*2+0] = make_float4(acc0[0], acc1[0], acc0[1], acc1[1]);
        O4[t*2+1] = make_float4(acc0[2], acc1[2], acc0[3], acc1[3]);
    } else {
        // generic tail (not hit for B = 2,000,000)
        for (int e = base; e < B; ++e) {
            float s0, c0, s1, c1;
            __sincosf(x[e*3+0], &s0, &c0);
            __sincosf(x[e*3+1], &s1, &c1);
            float p00 = c0*c1, p01 = c0*s1, p10 = s0*c1, p11 = s0*s1;
            float A0 = b2a, A1 = b2b;
            for (int l = 0; l < 32; ++l) {
                const float* row = ltf + l*12;
                float h = row[8];
                h = fmaf(row[0], c1,  h);
                h = fmaf(row[1], s1,  h);
                h = fmaf(row[2], c0,  h);
                h = fmaf(row[3], s0,  h);
                h = fmaf(row[4], p00, h);
                h = fmaf(row[5], p01, h);
                h = fmaf(row[6], p10, h);
                h = fmaf(row[7], p11, h);
                h = fmaxf(h, 0.f);
                A0 = fmaf(h, row[9],  A0);
                A1 = fmaf(h, row[10], A1);
            }
            out[e*2+0] = A0;
            out[e*2+1] = A1;
        }
    }
}

extern "C" void kernel_launch(void* const* d_in, const int* in_sizes, int n_in,
                              void* d_out, int out_size, void* d_ws, size_t ws_size,
                              hipStream_t stream) {
    const float* x     = (const float*)d_in[0];
    const float* theta = (const float*)d_in[1];
    const float* W1    = (const float*)d_in[2];
    const float* b1    = (const float*)d_in[3];
    const float* W2    = (const float*)d_in[4];
    const float* b2    = (const float*)d_in[5];
    float* out = (float*)d_out;
    float* tab = (float*)d_ws;

    const int B = in_sizes[0] / 3;

    q_precompute<<<1, 64, 0, stream>>>(theta, W1, b1, W2, b2, tab);

    const int nT = (B + 3) / 4;
    const int blocks = (nT + 255) / 256;
    q_main<<<blocks, 256, 0, stream>>>(x, tab, out, B);
}

// Round 2
// 104.141 us; speedup vs baseline: 1.0973x; 1.0973x over previous
//
#include <hip/hip_runtime.h>

// ---------------------------------------------------------------------------
// Single fused kernel. Every block redundantly rebuilds the 392-float
// coefficient table in LDS (~0.4 us, one wave, overlapped across blocks),
// then each thread processes 8 elements:
//   preact_l = bias_l + T_l . (1,cos x0,sin x0) (x) (1,cos x1,sin x1)
//   out = W2^T relu(preact) + b2
// x[:,2] is provably dead (global phase). 8 elems/thread makes the K-loop
// VALU-bound (88 VALU instrs per 3 broadcast ds_read_b128).
// Table layout (floats): row l (stride 12): [T01 T02 T10 T20 T11 T12 T21 T22
//   bias w2_l0 w2_l1 pad]; [384..385] = b2.
// ---------------------------------------------------------------------------
__global__ __launch_bounds__(256, 4) void q_fused(
    const float* __restrict__ x,
    const float* __restrict__ theta,
    const float* __restrict__ W1,   // (8,32)
    const float* __restrict__ b1,   // (32,)
    const float* __restrict__ W2,   // (32,2)
    const float* __restrict__ b2,   // (2,)
    float* __restrict__ out,
    int B)
{
    __shared__ float Ure[8][8];
    __shared__ float Uim[8][8];
    __shared__ float4 lt4[98];      // 392 floats

    const int lid  = threadIdx.x;
    const int t    = blockIdx.x * 256 + lid;
    const int base = t * 8;
    const bool full = (base + 8 <= B);

    // Issue the global x loads FIRST so VMEM latency hides behind table build.
    float4 xa[6];
    if (full) {
        const float4* X4 = (const float4*)x;
        #pragma unroll
        for (int i = 0; i < 6; ++i) xa[i] = X4[t*6 + i];
    }

    // ---- Phase 1: threads 0..7 build column `lid` of the fixed 8x8 unitary
    if (lid < 8) {
        float cr[8], ci[8];
        #pragma unroll
        for (int r = 0; r < 8; ++r) { cr[r] = (r == lid) ? 1.f : 0.f; ci[r] = 0.f; }

        auto rxmix = [&](int a, int b, float c_, float s_) {   // RX pair
            float ar = cr[a], ai = ci[a], br = cr[b], bi = ci[b];
            cr[a] = c_*ar + s_*bi;   ci[a] = c_*ai - s_*br;
            cr[b] = s_*ai + c_*br;   ci[b] = -s_*ar + c_*bi;
        };
        auto rymix = [&](int a, int b, float c_, float s_) {   // RY pair
            float ar = cr[a], ai = ci[a], br = cr[b], bi = ci[b];
            cr[a] = c_*ar - s_*br;   ci[a] = c_*ai - s_*bi;
            cr[b] = s_*ar + c_*br;   ci[b] = s_*ai + c_*bi;
        };
        auto zmul = [&](int r, float u, float v) {             // row *= (u+iv)
            float xr = cr[r], xi = ci[r];
            cr[r] = xr*u - xi*v;  ci[r] = xr*v + xi*u;
        };

        float c, s;
        // index = 4*i0 + 2*i1 + i2  (wire0 = MSB)
        __sincosf(theta[0]*0.5f, &s, &c);                       // RX wire0
        rxmix(0,4,c,s); rxmix(1,5,c,s); rxmix(2,6,c,s); rxmix(3,7,c,s);
        __sincosf(theta[1]*0.5f, &s, &c);                       // RY wire1
        rymix(0,2,c,s); rymix(1,3,c,s); rymix(4,6,c,s); rymix(5,7,c,s);
        __sincosf(theta[2]*0.5f, &s, &c);                       // RZ wire2
        #pragma unroll
        for (int r = 0; r < 8; ++r) zmul(r, c, (r & 1) ? s : -s);
        __sincosf(theta[3]*0.5f, &s, &c);                       // CRX 0->1
        rxmix(4,6,c,s); rxmix(5,7,c,s);
        __sincosf(theta[4]*0.5f, &s, &c);                       // RY wire2
        rymix(0,1,c,s); rymix(2,3,c,s); rymix(4,5,c,s); rymix(6,7,c,s);
        __sincosf(theta[5]*0.5f, &s, &c);                       // RX wire1
        rxmix(0,2,c,s); rxmix(1,3,c,s); rxmix(4,6,c,s); rxmix(5,7,c,s);
        __sincosf(theta[6]*0.5f, &s, &c);                       // CRX 1->2
        rxmix(2,3,c,s); rxmix(6,7,c,s);
        __sincosf(theta[7]*0.5f, &s, &c);                       // RZ wire0
        #pragma unroll
        for (int r = 0; r < 8; ++r) zmul(r, c, (r < 4) ? -s : s);

        #pragma unroll
        for (int r = 0; r < 8; ++r) { Ure[r][lid] = cr[r]; Uim[r][lid] = ci[r]; }
    }
    __syncthreads();

    // ---- Phase 2: threads 0..31 contract |U psi|^2 with W1/b1/W2 -> table
    if (lid < 32) {
        // W[:,m] = U[:,col(m)] * phase, col = {0,2,4,6}, phase = {1,1,-i,-i}
        float Wre[8][4], Wim[8][4];
        #pragma unroll
        for (int j = 0; j < 8; ++j) {
            Wre[j][0] =  Ure[j][0]; Wim[j][0] =  Uim[j][0];
            Wre[j][1] =  Ure[j][2]; Wim[j][1] =  Uim[j][2];
            Wre[j][2] =  Uim[j][4]; Wim[j][2] = -Ure[j][4];
            Wre[j][3] =  Uim[j][6]; Wim[j][3] = -Ure[j][6];
        }
        float Q[4][4];
        #pragma unroll
        for (int m = 0; m < 4; ++m)
            #pragma unroll
            for (int n = 0; n < 4; ++n) Q[m][n] = 0.f;
        #pragma unroll
        for (int j = 0; j < 8; ++j) {
            float w = W1[j*32 + lid];
            #pragma unroll
            for (int m = 0; m < 4; ++m)
                #pragma unroll
                for (int n = 0; n < 4; ++n)
                    Q[m][n] = fmaf(w, Wre[j][m]*Wre[j][n] + Wim[j][m]*Wim[j][n], Q[m][n]);
        }
        float R[3][3];
        R[0][0] = Q[0][0];
        R[0][1] = Q[0][1] + Q[1][0];
        R[0][2] = Q[1][1];
        R[1][0] = Q[0][2] + Q[2][0];
        R[1][1] = Q[0][3] + Q[1][2] + Q[2][1] + Q[3][0];
        R[1][2] = Q[1][3] + Q[3][1];
        R[2][0] = Q[2][2];
        R[2][1] = Q[2][3] + Q[3][2];
        R[2][2] = Q[3][3];
        float P[3][3];
        #pragma unroll
        for (int b = 0; b < 3; ++b) {
            P[0][b] = 0.5f*(R[0][b] + R[2][b]);
            P[1][b] = 0.5f*(R[0][b] - R[2][b]);
            P[2][b] = 0.5f*R[1][b];
        }
        float T[3][3];
        #pragma unroll
        for (int si = 0; si < 3; ++si) {
            T[si][0] = 0.5f*(P[si][0] + P[si][2]);
            T[si][1] = 0.5f*(P[si][0] - P[si][2]);
            T[si][2] = 0.5f*P[si][1];
        }
        float* row = ((float*)lt4) + lid*12;
        row[0] = T[0][1]; row[1] = T[0][2]; row[2] = T[1][0]; row[3] = T[2][0];
        row[4] = T[1][1]; row[5] = T[1][2]; row[6] = T[2][1]; row[7] = T[2][2];
        row[8] = b1[lid] + T[0][0];
        row[9]  = W2[lid*2+0];
        row[10] = W2[lid*2+1];
        row[11] = 0.f;
    }
    if (lid == 0) {
        float* f = (float*)lt4;
        f[384] = b2[0]; f[385] = b2[1]; f[386] = 0.f; f[387] = 0.f;
        f[388] = 0.f;   f[389] = 0.f;   f[390] = 0.f; f[391] = 0.f;
    }
    __syncthreads();

    const float* ltf = (const float*)lt4;
    const float b2a = ltf[384], b2b = ltf[385];

    if (full) {
        const float* xf = (const float*)xa;
        float C0[8], S0[8], C1[8], S1[8], Pcc[8], Pcs[8], Psc[8], Pss[8];
        #pragma unroll
        for (int k = 0; k < 8; ++k) {
            __sincosf(xf[3*k+0], &S0[k], &C0[k]);
            __sincosf(xf[3*k+1], &S1[k], &C1[k]);
            Pcc[k] = C0[k]*C1[k]; Pcs[k] = C0[k]*S1[k];
            Psc[k] = S0[k]*C1[k]; Pss[k] = S0[k]*S1[k];
        }
        float acc0[8], acc1[8];
        #pragma unroll
        for (int k = 0; k < 8; ++k) { acc0[k] = b2a; acc1[k] = b2b; }

        #pragma unroll 1
        for (int l = 0; l < 32; ++l) {
            float4 cA = lt4[l*3+0];   // T01 T02 T10 T20
            float4 cB = lt4[l*3+1];   // T11 T12 T21 T22
            float4 cC = lt4[l*3+2];   // bias w2a w2b pad
            #pragma unroll
            for (int k = 0; k < 8; ++k) {
                float h = cC.x;
                h = fmaf(cA.x, C1[k],  h);
                h = fmaf(cA.y, S1[k],  h);
                h = fmaf(cA.z, C0[k],  h);
                h = fmaf(cA.w, S0[k],  h);
                h = fmaf(cB.x, Pcc[k], h);
                h = fmaf(cB.y, Pcs[k], h);
                h = fmaf(cB.z, Psc[k], h);
                h = fmaf(cB.w, Pss[k], h);
                h = fmaxf(h, 0.f);
                acc0[k] = fmaf(h, cC.y, acc0[k]);
                acc1[k] = fmaf(h, cC.z, acc1[k]);
            }
        }
        float4* O4 = (float4*)out;
        #pragma unroll
        for (int k = 0; k < 4; ++k)
            O4[t*4+k] = make_float4(acc0[2*k], acc1[2*k], acc0[2*k+1], acc1[2*k+1]);
    } else if (base < B) {
        // generic scalar tail (not hit for B = 2,000,000)
        for (int e = base; e < B; ++e) {
            float s0, c0, s1, c1;
            __sincosf(x[e*3+0], &s0, &c0);
            __sincosf(x[e*3+1], &s1, &c1);
            float pcc = c0*c1, pcs = c0*s1, psc = s0*c1, pss = s0*s1;
            float A0 = b2a, A1 = b2b;
            for (int l = 0; l < 32; ++l) {
                const float* row = ltf + l*12;
                float h = row[8];
                h = fmaf(row[0], c1,  h);
                h = fmaf(row[1], s1,  h);
                h = fmaf(row[2], c0,  h);
                h = fmaf(row[3], s0,  h);
                h = fmaf(row[4], pcc, h);
                h = fmaf(row[5], pcs, h);
                h = fmaf(row[6], psc, h);
                h = fmaf(row[7], pss, h);
                h = fmaxf(h, 0.f);
                A0 = fmaf(h, row[9],  A0);
                A1 = fmaf(h, row[10], A1);
            }
            out[e*2+0] = A0;
            out[e*2+1] = A1;
        }
    }
}

extern "C" void kernel_launch(void* const* d_in, const int* in_sizes, int n_in,
                              void* d_out, int out_size, void* d_ws, size_t ws_size,
                              hipStream_t stream) {
    const float* x     = (const float*)d_in[0];
    const float* theta = (const float*)d_in[1];
    const float* W1    = (const float*)d_in[2];
    const float* b1    = (const float*)d_in[3];
    const float* W2    = (const float*)d_in[4];
    const float* b2    = (const float*)d_in[5];
    float* out = (float*)d_out;

    const int B = in_sizes[0] / 3;
    const int nT = (B + 7) / 8;
    const int blocks = (nT + 255) / 256;
    q_fused<<<blocks, 256, 0, stream>>>(x, theta, W1, b1, W2, b2, out, B);
}